// Round 2
// baseline (788.482 us; speedup 1.0000x reference)
//
#include <hip/hip_runtime.h>
#include <hip/hip_bf16.h>

// MetaNetImageEncoder on MI355X — round 2.
// Changes vs round 1:
//  * k_mix: per-sample mixed weights nW1T[b] = W1T + sum_t c_t dW1T precomputed once
//    (reads weight set once, streams 75.5MB writes) -> phase B GEMM is clean.
//    Fallback to inline mixing if ws_size too small.
//  * k_gemm_pool: BM 128/96 (row-split, M/sample 256->224), BN=128, BK=64,
//    2x2 wave grid (32 MFMA/wave/barrier), XOR-swizzled LDS granule layout,
//    grid 768 = 3 blocks/CU, pooling via atomicAdd into zeroed f32.
//  * k_base_metanet: fused base=pooled@W2+b2 and MetaNet (reads f32 W2/mw1 coalesced).
//
// MFMA 16x16x32 bf16 layouts (learn_hip m89):
//   A-frag: A[m=lane&15][k=(lane>>4)*8+j], B-frag: B[k=(lane>>4)*8+j][n=lane&15]
//   C/D:    col=lane&15, row=(lane>>4)*4+reg

typedef __bf16 bf16x8 __attribute__((ext_vector_type(8)));
typedef float f32x4 __attribute__((ext_vector_type(4)));
typedef __hip_bfloat16 bf16;

struct alignas(16) BF8 { bf16 h[8]; };

constexpr int BATCH = 64;
constexpr int NP    = 196;    // patches per image (14x14)
constexpr int NPAD  = 256;    // padded rows per sample in A_bf
constexpr int DIM   = 768;
constexpr int NT    = 8;
constexpr size_t MSZ = (size_t)DIM * DIM;   // 589824 elems per matrix

// ---------------- K1: patchify + cast to bf16, pad rows to 256 ----------------
__global__ void k_patchify(const float* __restrict__ x, bf16* __restrict__ A) {
  int idx  = blockIdx.x * blockDim.x + threadIdx.x;
  int col4 = idx % (DIM / 4);
  int row  = idx / (DIM / 4);
  int d = col4 * 4;
  int b = row >> 8;
  int n = row & 255;
  bf16 tmp[4];
  if (n < NP) {
    int hp = n / 14, wp = n % 14;
    int c  = d >> 8;
    int rr = d & 255;
    int i = rr >> 4, j = rr & 15;
    const float* src = x + ((((size_t)b * 3 + c) * 224 + hp * 16 + i) * 224 + wp * 16 + j);
    float4 f = *(const float4*)src;
    tmp[0] = __float2bfloat16(f.x);
    tmp[1] = __float2bfloat16(f.y);
    tmp[2] = __float2bfloat16(f.z);
    tmp[3] = __float2bfloat16(f.w);
  } else {
    tmp[0] = tmp[1] = tmp[2] = tmp[3] = __float2bfloat16(0.0f);
  }
  *(ushort4*)(A + (size_t)row * DIM + d) = *(ushort4*)tmp;
}

// ---------------- K2: transpose + cast weights: WT[mat][n][k] = W[mat][k][n] ----------------
__global__ void k_transpose_cast(const float* __restrict__ W1, const float* __restrict__ dW1,
                                 const float* __restrict__ W2, const float* __restrict__ dW2,
                                 bf16* __restrict__ WT) {
  __shared__ float tile[32][33];
  int mat = blockIdx.z;
  const float* src;
  if      (mat == 0) src = W1;
  else if (mat <= 8) src = dW1 + (size_t)(mat - 1) * MSZ;
  else if (mat == 9) src = W2;
  else               src = dW2 + (size_t)(mat - 10) * MSZ;
  int n0 = blockIdx.x * 32;
  int k0 = blockIdx.y * 32;
  int tx = threadIdx.x & 31, ty = threadIdx.x >> 5;
#pragma unroll
  for (int r = ty; r < 32; r += 8)
    tile[r][tx] = src[(size_t)(k0 + r) * DIM + n0 + tx];
  __syncthreads();
  bf16* dst = WT + (size_t)mat * MSZ;
#pragma unroll
  for (int r = ty; r < 32; r += 8)
    dst[(size_t)(n0 + r) * DIM + k0 + tx] = __float2bfloat16(tile[tx][r]);
}

// ---------------- K-mix: nW1T[b] = W1T + sum_t c_t dW1T_t  (bf16, [n][k]) ----------------
// grid 576 x 256: each block covers 128 granules (of 8 bf16); thread-halves split samples.
__global__ void k_mix(const bf16* __restrict__ WT, const float* __restrict__ coefs,
                      bf16* __restrict__ nW1T) {
  __shared__ float cls[BATCH * NT];
  int tid = threadIdx.x;
  cls[tid]       = coefs[tid];
  cls[tid + 256] = coefs[tid + 256];
  __syncthreads();
  size_t g  = (size_t)blockIdx.x * 128 + (tid & 127);
  int    b0 = (tid >> 7) * 32;
  const bf16* p = WT + g * 8;
  BF8 wv = *(const BF8*)p;
  float w[8], d[NT][8];
#pragma unroll
  for (int i = 0; i < 8; i++) w[i] = __bfloat162float(wv.h[i]);
#pragma unroll
  for (int t = 0; t < NT; t++) {
    BF8 dv = *(const BF8*)(p + (size_t)(1 + t) * MSZ);
#pragma unroll
    for (int i = 0; i < 8; i++) d[t][i] = __bfloat162float(dv.h[i]);
  }
  for (int b = b0; b < b0 + 32; b++) {
    float m[8];
#pragma unroll
    for (int i = 0; i < 8; i++) m[i] = w[i];
#pragma unroll
    for (int t = 0; t < NT; t++) {
      float c = cls[b * NT + t];
#pragma unroll
      for (int i = 0; i < 8; i++) m[i] += c * d[t][i];
    }
    BF8 o;
#pragma unroll
    for (int i = 0; i < 8; i++) o.h[i] = __float2bfloat16(m[i]);
    *(BF8*)(nW1T + (size_t)b * MSZ + g * 8) = o;
  }
}

// ---------------- K3: per-sample GEMM + relu + masked column-mean (atomic pool) ----------------
// grid (64 samples, 2 row-blocks, 6 n-tiles) = 768 blocks. BM=128/96, BN=128, BK=64.
// 2x2 wave grid: wave (wr,wc) owns 64(or 48) rows x 64 cols.
// LDS: XOR-swizzled 16B granules: slot(r,c) = r*8 + (c ^ (r&7)).

template<int MFR>
__device__ __forceinline__ void gp_kloop(const bf16* As, const bf16* Bs, int wrow0, int wc,
                                         int quad, int l16, f32x4 acc[4][4]) {
#pragma unroll
  for (int ks = 0; ks < 2; ks++) {
    bf16x8 bfr[4];
#pragma unroll
    for (int nf = 0; nf < 4; nf++) {
      int rrow = wc * 64 + nf * 16 + l16;
      bfr[nf] = *(const bf16x8*)(Bs + (size_t)(rrow * 8 + ((ks * 4 + quad) ^ (rrow & 7))) * 8);
    }
#pragma unroll
    for (int mf = 0; mf < MFR; mf++) {
      int arow = wrow0 + mf * 16 + l16;
      bf16x8 af = *(const bf16x8*)(As + (size_t)(arow * 8 + ((ks * 4 + quad) ^ (arow & 7))) * 8);
#pragma unroll
      for (int nf = 0; nf < 4; nf++)
        acc[mf][nf] = __builtin_amdgcn_mfma_f32_16x16x32_bf16(af, bfr[nf], acc[mf][nf], 0, 0, 0);
    }
  }
}

__global__ __launch_bounds__(256, 3)
void k_gemm_pool(const bf16* __restrict__ A,      // [64*256, 768]
                 const bf16* __restrict__ Bsrc,   // W1T (shared) or nW1T (perSample)
                 int perSample,
                 const float* __restrict__ b1,
                 const float* __restrict__ db1,
                 const float* __restrict__ coefs, // null in phase A
                 int inlineMix,                   // 1 = mix from WT mats 0..8 at staging
                 float* __restrict__ pooled) {    // f32 [64][768], pre-zeroed, atomicAdd
  __shared__ uint4 AslU[128 * 8];
  __shared__ uint4 BslU[128 * 8];
  __shared__ float biasl[128];
  __shared__ float cl[NT];
  __shared__ float red[2][128];

  int b  = blockIdx.x;
  int rb = blockIdx.y;
  int n0 = blockIdx.z * 128;
  int tid = threadIdx.x;

  if (tid < NT) cl[tid] = coefs ? coefs[b * NT + tid] : 0.0f;
  __syncthreads();
  if (tid < 128) {
    float bias = b1[n0 + tid];
    if (coefs) {
#pragma unroll
      for (int t = 0; t < NT; t++) bias += cl[t] * db1[t * DIM + n0 + tid];
    }
    biasl[tid] = bias;
  }

  int rows    = rb ? 96 : 128;            // staged A rows
  int rowbase = rb * 128;                 // global sample-row base
  const bf16* Ag = A + ((size_t)b * NPAD + rowbase) * DIM;
  const bf16* Bg = Bsrc + (perSample ? (size_t)b * MSZ : 0);

  int wave = tid >> 6, lane = tid & 63;
  int quad = lane >> 4, l16 = lane & 15;
  int wr = wave >> 1, wc = wave & 1;
  int wrow0 = wr * (rb ? 48 : 64);

  f32x4 acc[4][4] = {};
  int nA = rows * 8;

  for (int k0 = 0; k0 < DIM; k0 += 64) {
    // stage A
    for (int g = tid; g < nA; g += 256) {
      int r = g >> 3, c = g & 7;
      uint4 v = *(const uint4*)(Ag + (size_t)r * DIM + k0 + c * 8);
      AslU[r * 8 + (c ^ (r & 7))] = v;
    }
    // stage B (128 n-rows x 64 k)
    if (!inlineMix) {
      for (int g = tid; g < 1024; g += 256) {
        int r = g >> 3, c = g & 7;
        uint4 v = *(const uint4*)(Bg + (size_t)(n0 + r) * DIM + k0 + c * 8);
        BslU[r * 8 + (c ^ (r & 7))] = v;
      }
    } else {
      for (int g = tid; g < 1024; g += 256) {
        int r = g >> 3, c = g & 7;
        const bf16* p0 = Bg + (size_t)(n0 + r) * DIM + k0 + c * 8;
        BF8 w = *(const BF8*)p0;
        float m[8];
#pragma unroll
        for (int i = 0; i < 8; i++) m[i] = __bfloat162float(w.h[i]);
#pragma unroll
        for (int t = 0; t < NT; t++) {
          BF8 dv = *(const BF8*)(p0 + (size_t)(1 + t) * MSZ);
          float c2 = cl[t];
#pragma unroll
          for (int i = 0; i < 8; i++) m[i] += c2 * __bfloat162float(dv.h[i]);
        }
        BF8 o;
#pragma unroll
        for (int i = 0; i < 8; i++) o.h[i] = __float2bfloat16(m[i]);
        BslU[r * 8 + (c ^ (r & 7))] = *(uint4*)&o;
      }
    }
    __syncthreads();
    const bf16* As = (const bf16*)AslU;
    const bf16* Bs = (const bf16*)BslU;
    if (rb == 0) gp_kloop<4>(As, Bs, wrow0, wc, quad, l16, acc);
    else         gp_kloop<3>(As, Bs, wrow0, wc, quad, l16, acc);
    __syncthreads();
  }

  // epilogue: relu(acc + bias), mask pad rows, column sums
  int mfr = rb ? 3 : 4;
  float colsum[4];
#pragma unroll
  for (int nf = 0; nf < 4; nf++) {
    float bias = biasl[wc * 64 + nf * 16 + l16];
    float s = 0.0f;
    for (int mf = 0; mf < mfr; mf++) {
      int rbase = rowbase + wrow0 + mf * 16 + quad * 4;
#pragma unroll
      for (int r = 0; r < 4; r++) {
        if (rbase + r < NP) s += fmaxf(acc[mf][nf][r] + bias, 0.0f);
      }
    }
    s += __shfl_xor(s, 16, 64);
    s += __shfl_xor(s, 32, 64);
    colsum[nf] = s;
  }
  if (lane < 16) {
#pragma unroll
    for (int nf = 0; nf < 4; nf++) red[wr][wc * 64 + nf * 16 + lane] = colsum[nf];
  }
  __syncthreads();
  if (tid < 128) {
    float s = red[0][tid] + red[1][tid];
    atomicAdd(pooled + (size_t)b * DIM + n0 + tid, s * (1.0f / 196.0f));
  }
}

// ---------------- K4: fused base + MetaNet, one block per sample ----------------
__global__ void k_base_metanet(const float* __restrict__ pooled,  // [64][768] f32
                               const float* __restrict__ W2,      // [768][768] f32 (k-major)
                               const float* __restrict__ b2,
                               const float* __restrict__ mw1, const float* __restrict__ mb1,
                               const float* __restrict__ mw2, const float* __restrict__ mb2,
                               float* __restrict__ coefs) {       // [64][8]
  __shared__ float pl[DIM];
  __shared__ float basel[DIM];
  __shared__ float hl[192];
  int b = blockIdx.x, tid = threadIdx.x;
  for (int i = tid; i < DIM; i += 256) pl[i] = pooled[(size_t)b * DIM + i];
  __syncthreads();
  float s0 = b2[tid], s1 = b2[tid + 256], s2 = b2[tid + 512];
  for (int k = 0; k < DIM; k++) {
    float pv = pl[k];
    const float* wr = W2 + (size_t)k * DIM;
    s0 += pv * wr[tid];
    s1 += pv * wr[tid + 256];
    s2 += pv * wr[tid + 512];
  }
  basel[tid] = s0; basel[tid + 256] = s1; basel[tid + 512] = s2;
  __syncthreads();
  if (tid < 192) {
    float h = mb1[tid];
    for (int k = 0; k < DIM; k++) h += basel[k] * mw1[(size_t)k * 192 + tid];
    hl[tid] = fmaxf(h, 0.0f);
  }
  __syncthreads();
  if (tid < NT) {
    float c = mb2[tid];
    for (int j = 0; j < 192; j++) c += hl[j] * mw2[(size_t)j * NT + tid];
    coefs[b * NT + tid] = c;
  }
}

// ---------------- K5: small GEMM, M=64: Y[mat] = pooled(f32) @ WT[9+mat] ----------------
__global__ __launch_bounds__(256, 2)
void k_gemm2(const float* __restrict__ Af,    // [64][768] f32
             const bf16* __restrict__ WT,
             float* __restrict__ Y) {         // [9][64][768]
  __shared__ uint4 AslU[64 * 8];
  __shared__ uint4 BslU[64 * 8];
  int n0  = blockIdx.x * 64;
  int mat = blockIdx.y;
  int tid = threadIdx.x, wave = tid >> 6, lane = tid & 63;
  int quad = lane >> 4, l16 = lane & 15;
  f32x4 acc[4] = {};
  const bf16* Wm = WT + (size_t)(9 + mat) * MSZ;
  for (int k0 = 0; k0 < DIM; k0 += 64) {
#pragma unroll
    for (int i = 0; i < 2; i++) {
      int g = tid + i * 256;
      int r = g >> 3, c = g & 7;
      const float* src = Af + (size_t)r * DIM + k0 + c * 8;
      float4 xa = ((const float4*)src)[0];
      float4 xb = ((const float4*)src)[1];
      BF8 o;
      o.h[0] = __float2bfloat16(xa.x); o.h[1] = __float2bfloat16(xa.y);
      o.h[2] = __float2bfloat16(xa.z); o.h[3] = __float2bfloat16(xa.w);
      o.h[4] = __float2bfloat16(xb.x); o.h[5] = __float2bfloat16(xb.y);
      o.h[6] = __float2bfloat16(xb.z); o.h[7] = __float2bfloat16(xb.w);
      AslU[r * 8 + (c ^ (r & 7))] = *(uint4*)&o;
      BslU[r * 8 + (c ^ (r & 7))] = *(const uint4*)(Wm + (size_t)(n0 + r) * DIM + k0 + c * 8);
    }
    __syncthreads();
    const bf16* As = (const bf16*)AslU;
    const bf16* Bs = (const bf16*)BslU;
#pragma unroll
    for (int ks = 0; ks < 2; ks++) {
      int brow = wave * 16 + l16;
      bf16x8 bfr = *(const bf16x8*)(Bs + (size_t)(brow * 8 + ((ks * 4 + quad) ^ (brow & 7))) * 8);
#pragma unroll
      for (int mf = 0; mf < 4; mf++) {
        int arow = mf * 16 + l16;
        bf16x8 af = *(const bf16x8*)(As + (size_t)(arow * 8 + ((ks * 4 + quad) ^ (arow & 7))) * 8);
        acc[mf] = __builtin_amdgcn_mfma_f32_16x16x32_bf16(af, bfr, acc[mf], 0, 0, 0);
      }
    }
    __syncthreads();
  }
#pragma unroll
  for (int mf = 0; mf < 4; mf++) {
#pragma unroll
    for (int r = 0; r < 4; r++) {
      int row = mf * 16 + quad * 4 + r;
      int col = n0 + wave * 16 + l16;
      Y[((size_t)mat * 64 + row) * DIM + col] = acc[mf][r];
    }
  }
}

// ---------------- K6: combine: out = Y0 + b2 + sum_t c_t (Y[1+t] + db2_t) ----------------
__global__ void k_combine(const float* __restrict__ Y,
                          const float* __restrict__ coefs,
                          const float* __restrict__ b2,
                          const float* __restrict__ db2,
                          float* __restrict__ out) {
  int idx = blockIdx.x * 256 + threadIdx.x;
  int b = idx / DIM, e = idx % DIM;
  float v = Y[(size_t)b * DIM + e] + b2[e];
#pragma unroll
  for (int t = 0; t < NT; t++) {
    float c = coefs[b * NT + t];
    v += c * (Y[((size_t)(1 + t) * 64 + b) * DIM + e] + db2[(size_t)t * DIM + e]);
  }
  out[idx] = v;
}

extern "C" void kernel_launch(void* const* d_in, const int* in_sizes, int n_in,
                              void* d_out, int out_size, void* d_ws, size_t ws_size,
                              hipStream_t stream) {
  const float* x   = (const float*)d_in[0];
  const float* W1  = (const float*)d_in[1];
  const float* b1  = (const float*)d_in[2];
  const float* W2  = (const float*)d_in[3];
  const float* b2  = (const float*)d_in[4];
  const float* dW1 = (const float*)d_in[5];
  const float* db1 = (const float*)d_in[6];
  const float* dW2 = (const float*)d_in[7];
  const float* db2 = (const float*)d_in[8];
  const float* mw1 = (const float*)d_in[9];
  const float* mb1 = (const float*)d_in[10];
  const float* mw2 = (const float*)d_in[11];
  const float* mb2 = (const float*)d_in[12];
  float* out = (float*)d_out;
  (void)in_sizes; (void)n_in; (void)out_size;

  // workspace layout (bytes)
  char* ws = (char*)d_ws;
  bf16*  A_bf    = (bf16*) (ws);                 // 25,165,824
  bf16*  WT      = (bf16*) (ws + 25165824);      // 21,233,664 -> 46,399,488
  float* pooledA = (float*)(ws + 46399488);      //    196,608 -> 46,596,096
  float* pooledB = (float*)(ws + 46596096);      //    196,608 -> 46,792,704
  float* coefs   = (float*)(ws + 46792704);      //      2,048 -> 46,794,752
  float* Y       = (float*)(ws + 46794752);      //  1,769,472 -> 48,564,224
  bf16*  nW1T    = (bf16*) (ws + 48564224);      // 75,497,472 -> 124,061,696
  const size_t NEED_BIG = 124061696;
  bool big = ws_size >= NEED_BIG;

  // zero pooled accumulators (contiguous)
  hipMemsetAsync(pooledA, 0, 2 * 196608, stream);

  k_patchify<<<dim3((BATCH * NPAD * (DIM / 4)) / 256), 256, 0, stream>>>(x, A_bf);
  k_transpose_cast<<<dim3(24, 24, 18), 256, 0, stream>>>(W1, dW1, W2, dW2, WT);
  // phase A
  k_gemm_pool<<<dim3(BATCH, 2, 6), 256, 0, stream>>>(A_bf, WT, 0, b1, db1, nullptr, 0, pooledA);
  k_base_metanet<<<dim3(BATCH), 256, 0, stream>>>(pooledA, W2, b2, mw1, mb1, mw2, mb2, coefs);
  // phase B
  if (big) {
    k_mix<<<dim3(576), 256, 0, stream>>>(WT, coefs, nW1T);
    k_gemm_pool<<<dim3(BATCH, 2, 6), 256, 0, stream>>>(A_bf, nW1T, 1, b1, db1, coefs, 0, pooledB);
  } else {
    k_gemm_pool<<<dim3(BATCH, 2, 6), 256, 0, stream>>>(A_bf, WT, 0, b1, db1, coefs, 1, pooledB);
  }
  k_gemm2<<<dim3(DIM / 64, 9), 256, 0, stream>>>(pooledB, WT, Y);
  k_combine<<<dim3((BATCH * DIM) / 256), 256, 0, stream>>>(Y, coefs, b2, db2, out);
}

// Round 3
// 479.439 us; speedup vs baseline: 1.6446x; 1.6446x over previous
//
#include <hip/hip_runtime.h>
#include <hip/hip_bf16.h>

// MetaNetImageEncoder on MI355X — round 3.
// Post-mortem r2: materializing nW1T (75.5MB) made k_gemm_pool HBM-bound
// (874 MB/dispatch, 218 us). Reverted to r1's inline-mix structure (B working
// set 10.6MB, L2-resident) and attacked r1's latency problem instead:
//   * BK 32->64: 32 MFMA/wave/barrier (was 16), 12 barriers (was 24)
//   * register prefetch of next k-tile across the barrier (global latency
//     hidden under MFMA phase)
//   * XOR-swizzled LDS granules (0 bank conflicts, vs 5.3M with +pad scheme)
//   * pooled as f32 direct store (no atomics, no memset)
//
// MFMA 16x16x32 bf16 layouts (learn_hip m89):
//   A-frag: A[m=lane&15][k=(lane>>4)*8+j], B-frag: B[k=(lane>>4)*8+j][n=lane&15]
//   C/D:    col=lane&15, row=(lane>>4)*4+reg

typedef __bf16 bf16x8 __attribute__((ext_vector_type(8)));
typedef float f32x4 __attribute__((ext_vector_type(4)));
typedef __hip_bfloat16 bf16;

struct alignas(16) BF8 { bf16 h[8]; };

constexpr int BATCH = 64;
constexpr int NP    = 196;    // patches per image (14x14)
constexpr int NPAD  = 256;    // padded rows per sample in A_bf
constexpr int DIM   = 768;
constexpr int NT    = 8;
constexpr size_t MSZ = (size_t)DIM * DIM;   // 589824 elems per matrix

// ---------------- K1: patchify + cast to bf16, pad rows to 256 ----------------
__global__ void k_patchify(const float* __restrict__ x, bf16* __restrict__ A) {
  int idx  = blockIdx.x * blockDim.x + threadIdx.x;
  int col4 = idx % (DIM / 4);
  int row  = idx / (DIM / 4);
  int d = col4 * 4;
  int b = row >> 8;
  int n = row & 255;
  bf16 tmp[4];
  if (n < NP) {
    int hp = n / 14, wp = n % 14;
    int c  = d >> 8;
    int rr = d & 255;
    int i = rr >> 4, j = rr & 15;
    const float* src = x + ((((size_t)b * 3 + c) * 224 + hp * 16 + i) * 224 + wp * 16 + j);
    float4 f = *(const float4*)src;
    tmp[0] = __float2bfloat16(f.x);
    tmp[1] = __float2bfloat16(f.y);
    tmp[2] = __float2bfloat16(f.z);
    tmp[3] = __float2bfloat16(f.w);
  } else {
    tmp[0] = tmp[1] = tmp[2] = tmp[3] = __float2bfloat16(0.0f);
  }
  *(ushort4*)(A + (size_t)row * DIM + d) = *(ushort4*)tmp;
}

// ---------------- K2: transpose + cast weights: WT[mat][n][k] = W[mat][k][n] ----------------
__global__ void k_transpose_cast(const float* __restrict__ W1, const float* __restrict__ dW1,
                                 const float* __restrict__ W2, const float* __restrict__ dW2,
                                 bf16* __restrict__ WT) {
  __shared__ float tile[32][33];
  int mat = blockIdx.z;
  const float* src;
  if      (mat == 0) src = W1;
  else if (mat <= 8) src = dW1 + (size_t)(mat - 1) * MSZ;
  else if (mat == 9) src = W2;
  else               src = dW2 + (size_t)(mat - 10) * MSZ;
  int n0 = blockIdx.x * 32;
  int k0 = blockIdx.y * 32;
  int tx = threadIdx.x & 31, ty = threadIdx.x >> 5;
#pragma unroll
  for (int r = ty; r < 32; r += 8)
    tile[r][tx] = src[(size_t)(k0 + r) * DIM + n0 + tx];
  __syncthreads();
  bf16* dst = WT + (size_t)mat * MSZ;
#pragma unroll
  for (int r = ty; r < 32; r += 8)
    dst[(size_t)(n0 + r) * DIM + k0 + tx] = __float2bfloat16(tile[tx][r]);
}

// ---------------- K3: per-sample GEMM (+inline mix) + relu + masked column-mean --------------
// grid (64 samples, 12 n-tiles of 64) = 768 blocks (3/CU). BM=256, BN=64, BK=64.
// 4 waves, wave w owns rows w*64..w*64+63, all 64 cols -> acc 4x4, 32 MFMA/barrier.
// LDS: XOR-swizzled 16B granules: slot(r,c) = r*8 + (c ^ (r&7)).  A 32KB + B 8KB.

template<int MIX>
__global__ __launch_bounds__(256, 3)
void k_gemm_pool(const bf16* __restrict__ A,    // [64*256, 768]
                 const bf16* __restrict__ WT,   // mats 0..8 = W1T, dW1T[8]
                 const float* __restrict__ b1,
                 const float* __restrict__ db1,
                 const float* __restrict__ coefs,  // [64][8] (MIX only)
                 float* __restrict__ pooled) {     // f32 [64][768]
  __shared__ uint4 AslU[256 * 8];
  __shared__ uint4 BslU[64 * 8];
  __shared__ float biasl[64];
  __shared__ float cl[NT];
  __shared__ float red[4][64];

  int b  = blockIdx.x;
  int n0 = blockIdx.y * 64;
  int tid = threadIdx.x;

  if (tid < NT) cl[tid] = MIX ? coefs[b * NT + tid] : 0.0f;
  __syncthreads();
  if (tid < 64) {
    float bias = b1[n0 + tid];
    if (MIX) {
#pragma unroll
      for (int t = 0; t < NT; t++) bias += cl[t] * db1[t * DIM + n0 + tid];
    }
    biasl[tid] = bias;
  }

  const bf16* Ag = A + (size_t)b * NPAD * DIM;
  int wave = tid >> 6, lane = tid & 63;
  int quad = lane >> 4, l16 = lane & 15;
  f32x4 acc[4][4] = {};

  int gr = tid >> 3, gc = tid & 7;         // granule (row, col) for i=0; i adds 32 rows
  uint4 pa[8];
  uint4 pb[2];

  // prefetch k-tile 0
#pragma unroll
  for (int i = 0; i < 8; i++)
    pa[i] = *(const uint4*)(Ag + (size_t)(gr + i * 32) * DIM + gc * 8);
  if (!MIX) {
#pragma unroll
    for (int i = 0; i < 2; i++)
      pb[i] = *(const uint4*)(WT + (size_t)(n0 + gr + i * 32) * DIM + gc * 8);
  }

  for (int kt = 0; kt < 12; kt++) {
    int k0 = kt * 64;
    // ---- stage prefetched A
#pragma unroll
    for (int i = 0; i < 8; i++) {
      int r = gr + i * 32;
      AslU[r * 8 + (gc ^ (r & 7))] = pa[i];
    }
    // ---- stage B (prefetched, or mixed on the fly from L2-resident mats)
    if (!MIX) {
#pragma unroll
      for (int i = 0; i < 2; i++) {
        int r = gr + i * 32;
        BslU[r * 8 + (gc ^ (r & 7))] = pb[i];
      }
    } else {
#pragma unroll
      for (int i = 0; i < 2; i++) {
        int r = gr + i * 32;
        const bf16* p0 = WT + (size_t)(n0 + r) * DIM + k0 + gc * 8;
        BF8 w = *(const BF8*)p0;
        float m[8];
#pragma unroll
        for (int j = 0; j < 8; j++) m[j] = __bfloat162float(w.h[j]);
#pragma unroll
        for (int t = 0; t < NT; t++) {
          BF8 dv = *(const BF8*)(p0 + (size_t)(1 + t) * MSZ);
          float cc = cl[t];
#pragma unroll
          for (int j = 0; j < 8; j++) m[j] += cc * __bfloat162float(dv.h[j]);
        }
        BF8 o;
#pragma unroll
        for (int j = 0; j < 8; j++) o.h[j] = __float2bfloat16(m[j]);
        BslU[r * 8 + (gc ^ (r & 7))] = *(uint4*)&o;
      }
    }
    __syncthreads();
    // ---- prefetch next k-tile (latency hidden under MFMA below)
    if (kt + 1 < 12) {
      int k1 = k0 + 64;
#pragma unroll
      for (int i = 0; i < 8; i++)
        pa[i] = *(const uint4*)(Ag + (size_t)(gr + i * 32) * DIM + k1 + gc * 8);
      if (!MIX) {
#pragma unroll
        for (int i = 0; i < 2; i++)
          pb[i] = *(const uint4*)(WT + (size_t)(n0 + gr + i * 32) * DIM + k1 + gc * 8);
      }
    }
    // ---- MFMA: 2 k-steps x 4 mf x 4 nf = 32 per wave
    const bf16* As = (const bf16*)AslU;
    const bf16* Bs = (const bf16*)BslU;
#pragma unroll
    for (int ks = 0; ks < 2; ks++) {
      bf16x8 bfr[4];
#pragma unroll
      for (int nf = 0; nf < 4; nf++) {
        int brow = nf * 16 + l16;
        bfr[nf] = *(const bf16x8*)(Bs + ((size_t)brow * 8 + ((ks * 4 + quad) ^ (brow & 7))) * 8);
      }
#pragma unroll
      for (int mf = 0; mf < 4; mf++) {
        int arow = wave * 64 + mf * 16 + l16;
        bf16x8 af = *(const bf16x8*)(As + ((size_t)arow * 8 + ((ks * 4 + quad) ^ (arow & 7))) * 8);
#pragma unroll
        for (int nf = 0; nf < 4; nf++)
          acc[mf][nf] = __builtin_amdgcn_mfma_f32_16x16x32_bf16(af, bfr[nf], acc[mf][nf], 0, 0, 0);
      }
    }
    __syncthreads();
  }

  // ---- epilogue: relu(acc + bias), mask pad rows, column sums
  int m0 = wave * 64;
  float colsum[4];
#pragma unroll
  for (int nf = 0; nf < 4; nf++) {
    float bias = biasl[nf * 16 + l16];
    float s = 0.0f;
#pragma unroll
    for (int mf = 0; mf < 4; mf++) {
      int rbase = m0 + mf * 16 + quad * 4;
#pragma unroll
      for (int r = 0; r < 4; r++) {
        if (rbase + r < NP) s += fmaxf(acc[mf][nf][r] + bias, 0.0f);
      }
    }
    s += __shfl_xor(s, 16, 64);
    s += __shfl_xor(s, 32, 64);
    colsum[nf] = s;
  }
  if (lane < 16) {
#pragma unroll
    for (int nf = 0; nf < 4; nf++) red[wave][nf * 16 + lane] = colsum[nf];
  }
  __syncthreads();
  if (tid < 64) {
    float s = red[0][tid] + red[1][tid] + red[2][tid] + red[3][tid];
    pooled[(size_t)b * DIM + n0 + tid] = s * (1.0f / 196.0f);
  }
}

// ---------------- K4: fused base + MetaNet, one block per sample ----------------
__global__ void k_base_metanet(const float* __restrict__ pooled,  // [64][768] f32
                               const float* __restrict__ W2,      // [768][768] f32 (k-major)
                               const float* __restrict__ b2,
                               const float* __restrict__ mw1, const float* __restrict__ mb1,
                               const float* __restrict__ mw2, const float* __restrict__ mb2,
                               float* __restrict__ coefs) {       // [64][8]
  __shared__ float pl[DIM];
  __shared__ float basel[DIM];
  __shared__ float hl[192];
  int b = blockIdx.x, tid = threadIdx.x;
  for (int i = tid; i < DIM; i += 256) pl[i] = pooled[(size_t)b * DIM + i];
  __syncthreads();
  float s0 = b2[tid], s1 = b2[tid + 256], s2 = b2[tid + 512];
  for (int k = 0; k < DIM; k++) {
    float pv = pl[k];
    const float* wr = W2 + (size_t)k * DIM;
    s0 += pv * wr[tid];
    s1 += pv * wr[tid + 256];
    s2 += pv * wr[tid + 512];
  }
  basel[tid] = s0; basel[tid + 256] = s1; basel[tid + 512] = s2;
  __syncthreads();
  if (tid < 192) {
    float h = mb1[tid];
    for (int k = 0; k < DIM; k++) h += basel[k] * mw1[(size_t)k * 192 + tid];
    hl[tid] = fmaxf(h, 0.0f);
  }
  __syncthreads();
  if (tid < NT) {
    float c = mb2[tid];
    for (int j = 0; j < 192; j++) c += hl[j] * mw2[(size_t)j * NT + tid];
    coefs[b * NT + tid] = c;
  }
}

// ---------------- K5: small GEMM, M=64: Y[mat] = pooled(f32) @ WT[9+mat] ----------------
__global__ __launch_bounds__(256, 2)
void k_gemm2(const float* __restrict__ Af,    // [64][768] f32
             const bf16* __restrict__ WT,
             float* __restrict__ Y) {         // [9][64][768]
  __shared__ uint4 AslU[64 * 8];
  __shared__ uint4 BslU[64 * 8];
  int n0  = blockIdx.x * 64;
  int mat = blockIdx.y;
  int tid = threadIdx.x, wave = tid >> 6, lane = tid & 63;
  int quad = lane >> 4, l16 = lane & 15;
  f32x4 acc[4] = {};
  const bf16* Wm = WT + (size_t)(9 + mat) * MSZ;
  for (int k0 = 0; k0 < DIM; k0 += 64) {
#pragma unroll
    for (int i = 0; i < 2; i++) {
      int g = tid + i * 256;
      int r = g >> 3, c = g & 7;
      const float* src = Af + (size_t)r * DIM + k0 + c * 8;
      float4 xa = ((const float4*)src)[0];
      float4 xb = ((const float4*)src)[1];
      BF8 o;
      o.h[0] = __float2bfloat16(xa.x); o.h[1] = __float2bfloat16(xa.y);
      o.h[2] = __float2bfloat16(xa.z); o.h[3] = __float2bfloat16(xa.w);
      o.h[4] = __float2bfloat16(xb.x); o.h[5] = __float2bfloat16(xb.y);
      o.h[6] = __float2bfloat16(xb.z); o.h[7] = __float2bfloat16(xb.w);
      AslU[r * 8 + (c ^ (r & 7))] = *(uint4*)&o;
      BslU[r * 8 + (c ^ (r & 7))] = *(const uint4*)(Wm + (size_t)(n0 + r) * DIM + k0 + c * 8);
    }
    __syncthreads();
    const bf16* As = (const bf16*)AslU;
    const bf16* Bs = (const bf16*)BslU;
#pragma unroll
    for (int ks = 0; ks < 2; ks++) {
      int brow = wave * 16 + l16;
      bf16x8 bfr = *(const bf16x8*)(Bs + (size_t)(brow * 8 + ((ks * 4 + quad) ^ (brow & 7))) * 8);
#pragma unroll
      for (int mf = 0; mf < 4; mf++) {
        int arow = mf * 16 + l16;
        bf16x8 af = *(const bf16x8*)(As + (size_t)(arow * 8 + ((ks * 4 + quad) ^ (arow & 7))) * 8);
        acc[mf] = __builtin_amdgcn_mfma_f32_16x16x32_bf16(af, bfr, acc[mf], 0, 0, 0);
      }
    }
    __syncthreads();
  }
#pragma unroll
  for (int mf = 0; mf < 4; mf++) {
#pragma unroll
    for (int r = 0; r < 4; r++) {
      int row = mf * 16 + quad * 4 + r;
      int col = n0 + wave * 16 + l16;
      Y[((size_t)mat * 64 + row) * DIM + col] = acc[mf][r];
    }
  }
}

// ---------------- K6: combine: out = Y0 + b2 + sum_t c_t (Y[1+t] + db2_t) ----------------
__global__ void k_combine(const float* __restrict__ Y,
                          const float* __restrict__ coefs,
                          const float* __restrict__ b2,
                          const float* __restrict__ db2,
                          float* __restrict__ out) {
  int idx = blockIdx.x * 256 + threadIdx.x;
  int b = idx / DIM, e = idx % DIM;
  float v = Y[(size_t)b * DIM + e] + b2[e];
#pragma unroll
  for (int t = 0; t < NT; t++) {
    float c = coefs[b * NT + t];
    v += c * (Y[((size_t)(1 + t) * 64 + b) * DIM + e] + db2[(size_t)t * DIM + e]);
  }
  out[idx] = v;
}

extern "C" void kernel_launch(void* const* d_in, const int* in_sizes, int n_in,
                              void* d_out, int out_size, void* d_ws, size_t ws_size,
                              hipStream_t stream) {
  const float* x   = (const float*)d_in[0];
  const float* W1  = (const float*)d_in[1];
  const float* b1  = (const float*)d_in[2];
  const float* W2  = (const float*)d_in[3];
  const float* b2  = (const float*)d_in[4];
  const float* dW1 = (const float*)d_in[5];
  const float* db1 = (const float*)d_in[6];
  const float* dW2 = (const float*)d_in[7];
  const float* db2 = (const float*)d_in[8];
  const float* mw1 = (const float*)d_in[9];
  const float* mb1 = (const float*)d_in[10];
  const float* mw2 = (const float*)d_in[11];
  const float* mb2 = (const float*)d_in[12];
  float* out = (float*)d_out;
  (void)in_sizes; (void)n_in; (void)out_size; (void)ws_size;

  // workspace layout (bytes) — total ~48.6 MB
  char* ws = (char*)d_ws;
  bf16*  A_bf    = (bf16*) (ws);                 // 25,165,824
  bf16*  WT      = (bf16*) (ws + 25165824);      // 21,233,664 -> 46,399,488
  float* pooledA = (float*)(ws + 46399488);      //    196,608 -> 46,596,096
  float* pooledB = (float*)(ws + 46596096);      //    196,608 -> 46,792,704
  float* coefs   = (float*)(ws + 46792704);      //      2,048 -> 46,794,752
  float* Y       = (float*)(ws + 46794752);      //  1,769,472 -> 48,564,224

  k_patchify<<<dim3((BATCH * NPAD * (DIM / 4)) / 256), 256, 0, stream>>>(x, A_bf);
  k_transpose_cast<<<dim3(24, 24, 18), 256, 0, stream>>>(W1, dW1, W2, dW2, WT);
  // phase A
  k_gemm_pool<0><<<dim3(BATCH, DIM / 64), 256, 0, stream>>>(A_bf, WT, b1, db1, nullptr, pooledA);
  k_base_metanet<<<dim3(BATCH), 256, 0, stream>>>(pooledA, W2, b2, mw1, mb1, mw2, mb2, coefs);
  // phase B (inline mix from L2-resident WT)
  k_gemm_pool<1><<<dim3(BATCH, DIM / 64), 256, 0, stream>>>(A_bf, WT, b1, db1, coefs, pooledB);
  k_gemm2<<<dim3(DIM / 64, 9), 256, 0, stream>>>(pooledB, WT, Y);
  k_combine<<<dim3((BATCH * DIM) / 256), 256, 0, stream>>>(Y, coefs, b2, db2, out);
}

// Round 4
// 307.825 us; speedup vs baseline: 2.5615x; 1.5575x over previous
//
#include <hip/hip_runtime.h>
#include <hip/hip_bf16.h>

// MetaNetImageEncoder on MI355X — round 4.
// Post-mortem r3: register prefetch (pa[8]) spilled to scratch every k-iter
// -> 302 MB of scratch writes per dispatch (WRITE_SIZE 295MB vs 0.2MB stored).
// Fix: stage via __builtin_amdgcn_global_load_lds width=16 (async global->LDS,
// zero staging VGPRs). XOR-swizzle kept by inverting it on the per-lane GLOBAL
// address (lds dst is lane-contiguous; swizzled granule fetched instead) —
// stays within the same 128B row window, so coalescing preserved.
// Phase-B B-tile still mixed in registers (L2-resident WT, ~20 live regs).
// Also: base GEMM via MFMA k_gemm2 (bf16 WT, 13MB) instead of fused f32
// W2-streaming kernel (144MB), + tiny k_metanet.
//
// MFMA 16x16x32 bf16 layouts (learn_hip m89):
//   A-frag: A[m=lane&15][k=(lane>>4)*8+j], B-frag: B[k=(lane>>4)*8+j][n=lane&15]
//   C/D:    col=lane&15, row=(lane>>4)*4+reg

typedef __bf16 bf16x8 __attribute__((ext_vector_type(8)));
typedef float f32x4 __attribute__((ext_vector_type(4)));
typedef __hip_bfloat16 bf16;

struct alignas(16) BF8 { bf16 h[8]; };

constexpr int BATCH = 64;
constexpr int NP    = 196;
constexpr int NPAD  = 256;
constexpr int DIM   = 768;
constexpr int NT    = 8;
constexpr size_t MSZ = (size_t)DIM * DIM;

__device__ __forceinline__ void async_cp16(const void* g, void* l) {
  __builtin_amdgcn_global_load_lds(
      (const __attribute__((address_space(1))) uint32_t*)g,
      (__attribute__((address_space(3))) uint32_t*)l, 16, 0, 0);
}

// ---------------- K1: patchify + cast to bf16, pad rows to 256 ----------------
__global__ void k_patchify(const float* __restrict__ x, bf16* __restrict__ A) {
  int idx  = blockIdx.x * blockDim.x + threadIdx.x;
  int col4 = idx % (DIM / 4);
  int row  = idx / (DIM / 4);
  int d = col4 * 4;
  int b = row >> 8;
  int n = row & 255;
  bf16 tmp[4];
  if (n < NP) {
    int hp = n / 14, wp = n % 14;
    int c  = d >> 8;
    int rr = d & 255;
    int i = rr >> 4, j = rr & 15;
    const float* src = x + ((((size_t)b * 3 + c) * 224 + hp * 16 + i) * 224 + wp * 16 + j);
    float4 f = *(const float4*)src;
    tmp[0] = __float2bfloat16(f.x);
    tmp[1] = __float2bfloat16(f.y);
    tmp[2] = __float2bfloat16(f.z);
    tmp[3] = __float2bfloat16(f.w);
  } else {
    tmp[0] = tmp[1] = tmp[2] = tmp[3] = __float2bfloat16(0.0f);
  }
  *(ushort4*)(A + (size_t)row * DIM + d) = *(ushort4*)tmp;
}

// ---------------- K2: transpose + cast weights: WT[mat][n][k] = W[mat][k][n] ----------------
__global__ void k_transpose_cast(const float* __restrict__ W1, const float* __restrict__ dW1,
                                 const float* __restrict__ W2, const float* __restrict__ dW2,
                                 bf16* __restrict__ WT) {
  __shared__ float tile[32][33];
  int mat = blockIdx.z;
  const float* src;
  if      (mat == 0) src = W1;
  else if (mat <= 8) src = dW1 + (size_t)(mat - 1) * MSZ;
  else if (mat == 9) src = W2;
  else               src = dW2 + (size_t)(mat - 10) * MSZ;
  int n0 = blockIdx.x * 32;
  int k0 = blockIdx.y * 32;
  int tx = threadIdx.x & 31, ty = threadIdx.x >> 5;
#pragma unroll
  for (int r = ty; r < 32; r += 8)
    tile[r][tx] = src[(size_t)(k0 + r) * DIM + n0 + tx];
  __syncthreads();
  bf16* dst = WT + (size_t)mat * MSZ;
#pragma unroll
  for (int r = ty; r < 32; r += 8)
    dst[(size_t)(n0 + r) * DIM + k0 + tx] = __float2bfloat16(tile[tx][r]);
}

// ---------------- K3: per-sample GEMM (+inline mix) + relu + masked column-mean --------------
// grid (64 samples, 12 n-tiles) = 768 blocks (3/CU). BM=256, BN=64, BK=64.
// LDS XOR-swizzled granules: slot(r,c) = r*8 + (c ^ (r&7)); staged via
// global_load_lds with the swizzle applied to the source address.

template<int MIX>
__global__ __launch_bounds__(256, 3)
void k_gemm_pool(const bf16* __restrict__ A,    // [64*256, 768]
                 const bf16* __restrict__ WT,   // mats 0..8 = W1T, dW1T[8]
                 const float* __restrict__ b1,
                 const float* __restrict__ db1,
                 const float* __restrict__ coefs,  // [64][8] (MIX only)
                 float* __restrict__ pooled) {     // f32 [64][768]
  __shared__ uint4 AslU[256 * 8];
  __shared__ uint4 BslU[64 * 8];
  __shared__ float biasl[64];
  __shared__ float cl[NT];
  __shared__ float red[4][64];

  int b  = blockIdx.x;
  int n0 = blockIdx.y * 64;
  int tid = threadIdx.x;

  if (MIX) {
    if (tid < NT) cl[tid] = coefs[b * NT + tid];
    __syncthreads();
  }
  if (tid < 64) {
    float bias = b1[n0 + tid];
    if (MIX) {
#pragma unroll
      for (int t = 0; t < NT; t++) bias += cl[t] * db1[t * DIM + n0 + tid];
    }
    biasl[tid] = bias;
  }
  float cr[NT];
  if (MIX) {
#pragma unroll
    for (int t = 0; t < NT; t++) cr[t] = cl[t];
  }

  const bf16* Ag = A + (size_t)b * NPAD * DIM;
  int wave = tid >> 6, lane = tid & 63;
  int quad = lane >> 4, l16 = lane & 15;
  f32x4 acc[4][4] = {};

  for (int kt = 0; kt < 12; kt++) {
    const bf16* Ak = Ag + kt * 64;
    const bf16* Wk = WT + kt * 64;
    // ---- stage A: async global->LDS, swizzle folded into source address
#pragma unroll
    for (int i = 0; i < 8; i++) {
      int s = wave * 512 + i * 64 + lane;
      int r = s >> 3, c = (s & 7) ^ (r & 7);
      async_cp16(Ak + (size_t)r * DIM + c * 8, (void*)(AslU + wave * 512 + i * 64));
    }
    // ---- stage B
    if (!MIX) {
#pragma unroll
      for (int i = 0; i < 2; i++) {
        int s = wave * 128 + i * 64 + lane;
        int r = s >> 3, c = (s & 7) ^ (r & 7);
        async_cp16(Wk + (size_t)(n0 + r) * DIM + c * 8, (void*)(BslU + wave * 128 + i * 64));
      }
    } else {
#pragma unroll
      for (int i = 0; i < 2; i++) {
        int g = tid + 256 * i;
        int r = g >> 3, c = (g & 7) ^ (r & 7);
        const bf16* p0 = Wk + (size_t)(n0 + r) * DIM + c * 8;
        BF8 w = *(const BF8*)p0;
        float m[8];
#pragma unroll
        for (int j = 0; j < 8; j++) m[j] = __bfloat162float(w.h[j]);
#pragma unroll
        for (int t = 0; t < NT; t++) {
          BF8 dv = *(const BF8*)(p0 + (size_t)(1 + t) * MSZ);
          float cc = cr[t];
#pragma unroll
          for (int j = 0; j < 8; j++) m[j] += cc * __bfloat162float(dv.h[j]);
        }
        BF8 o;
#pragma unroll
        for (int j = 0; j < 8; j++) o.h[j] = __float2bfloat16(m[j]);
        BslU[g] = *(uint4*)&o;
      }
    }
    __syncthreads();   // drains vmcnt (async LDS loads) + lgkm (ds_write)
    // ---- MFMA: 2 k-steps x 4 mf x 4 nf = 32 per wave
    const bf16* As = (const bf16*)AslU;
    const bf16* Bs = (const bf16*)BslU;
#pragma unroll
    for (int ks = 0; ks < 2; ks++) {
      bf16x8 bfr[4];
#pragma unroll
      for (int nf = 0; nf < 4; nf++) {
        int brow = nf * 16 + l16;
        bfr[nf] = *(const bf16x8*)(Bs + ((size_t)brow * 8 + ((ks * 4 + quad) ^ (brow & 7))) * 8);
      }
#pragma unroll
      for (int mf = 0; mf < 4; mf++) {
        int arow = wave * 64 + mf * 16 + l16;
        bf16x8 af = *(const bf16x8*)(As + ((size_t)arow * 8 + ((ks * 4 + quad) ^ (arow & 7))) * 8);
#pragma unroll
        for (int nf = 0; nf < 4; nf++)
          acc[mf][nf] = __builtin_amdgcn_mfma_f32_16x16x32_bf16(af, bfr[nf], acc[mf][nf], 0, 0, 0);
      }
    }
    __syncthreads();
  }

  // ---- epilogue: relu(acc + bias), mask pad rows, column sums
  int m0 = wave * 64;
  float colsum[4];
#pragma unroll
  for (int nf = 0; nf < 4; nf++) {
    float bias = biasl[nf * 16 + l16];
    float s = 0.0f;
#pragma unroll
    for (int mf = 0; mf < 4; mf++) {
      int rbase = m0 + mf * 16 + quad * 4;
#pragma unroll
      for (int r = 0; r < 4; r++) {
        if (rbase + r < NP) s += fmaxf(acc[mf][nf][r] + bias, 0.0f);
      }
    }
    s += __shfl_xor(s, 16, 64);
    s += __shfl_xor(s, 32, 64);
    colsum[nf] = s;
  }
  if (lane < 16) {
#pragma unroll
    for (int nf = 0; nf < 4; nf++) red[wave][nf * 16 + lane] = colsum[nf];
  }
  __syncthreads();
  if (tid < 64) {
    float s = red[0][tid] + red[1][tid] + red[2][tid] + red[3][tid];
    pooled[(size_t)b * DIM + n0 + tid] = s * (1.0f / 196.0f);
  }
}

// ---------------- K5: small GEMM, M=64: Y[mat] = Af(f32->bf16) @ WT[matbase+mat] ------------
__global__ __launch_bounds__(256, 2)
void k_gemm2(const float* __restrict__ Af,    // [64][768] f32
             const bf16* __restrict__ WT,
             int matbase,
             const float* __restrict__ bias,  // [768] or null
             float* __restrict__ Y) {         // [nmat][64][768]
  __shared__ uint4 AslU[64 * 8];
  __shared__ uint4 BslU[64 * 8];
  int n0  = blockIdx.x * 64;
  int mat = blockIdx.y;
  int tid = threadIdx.x, wave = tid >> 6, lane = tid & 63;
  int quad = lane >> 4, l16 = lane & 15;
  f32x4 acc[4] = {};
  const bf16* Wm = WT + (size_t)(matbase + mat) * MSZ;
  for (int k0 = 0; k0 < DIM; k0 += 64) {
#pragma unroll
    for (int i = 0; i < 2; i++) {
      int g = tid + i * 256;
      int r = g >> 3, c = g & 7;
      const float* src = Af + (size_t)r * DIM + k0 + c * 8;
      float4 xa = ((const float4*)src)[0];
      float4 xb = ((const float4*)src)[1];
      BF8 o;
      o.h[0] = __float2bfloat16(xa.x); o.h[1] = __float2bfloat16(xa.y);
      o.h[2] = __float2bfloat16(xa.z); o.h[3] = __float2bfloat16(xa.w);
      o.h[4] = __float2bfloat16(xb.x); o.h[5] = __float2bfloat16(xb.y);
      o.h[6] = __float2bfloat16(xb.z); o.h[7] = __float2bfloat16(xb.w);
      AslU[r * 8 + (c ^ (r & 7))] = *(uint4*)&o;
      BslU[r * 8 + (c ^ (r & 7))] = *(const uint4*)(Wm + (size_t)(n0 + r) * DIM + k0 + c * 8);
    }
    __syncthreads();
    const bf16* As = (const bf16*)AslU;
    const bf16* Bs = (const bf16*)BslU;
#pragma unroll
    for (int ks = 0; ks < 2; ks++) {
      int brow = wave * 16 + l16;
      bf16x8 bfr = *(const bf16x8*)(Bs + (size_t)(brow * 8 + ((ks * 4 + quad) ^ (brow & 7))) * 8);
#pragma unroll
      for (int mf = 0; mf < 4; mf++) {
        int arow = mf * 16 + l16;
        bf16x8 af = *(const bf16x8*)(As + (size_t)(arow * 8 + ((ks * 4 + quad) ^ (arow & 7))) * 8);
        acc[mf] = __builtin_amdgcn_mfma_f32_16x16x32_bf16(af, bfr, acc[mf], 0, 0, 0);
      }
    }
    __syncthreads();
  }
#pragma unroll
  for (int mf = 0; mf < 4; mf++) {
#pragma unroll
    for (int r = 0; r < 4; r++) {
      int row = mf * 16 + quad * 4 + r;
      int col = n0 + wave * 16 + l16;
      float v = acc[mf][r];
      if (bias) v += bias[col];
      Y[((size_t)mat * 64 + row) * DIM + col] = v;
    }
  }
}

// ---------------- K6: MetaNet: coefs = relu(base@mw1+mb1)@mw2 + mb2 ----------------
__global__ void k_metanet(const float* __restrict__ base,  // [64][768]
                          const float* __restrict__ mw1, const float* __restrict__ mb1,
                          const float* __restrict__ mw2, const float* __restrict__ mb2,
                          float* __restrict__ coefs) {     // [64][8]
  __shared__ float bl[DIM];
  __shared__ float hl[192];
  int b = blockIdx.x, tid = threadIdx.x;   // 192 threads
  for (int i = tid; i < DIM; i += 192) bl[i] = base[(size_t)b * DIM + i];
  __syncthreads();
  float s = mb1[tid];
  for (int k = 0; k < DIM; k++) s += bl[k] * mw1[(size_t)k * 192 + tid];
  hl[tid] = fmaxf(s, 0.0f);
  __syncthreads();
  if (tid < NT) {
    float c = mb2[tid];
    for (int j = 0; j < 192; j++) c += hl[j] * mw2[(size_t)j * NT + tid];
    coefs[b * NT + tid] = c;
  }
}

// ---------------- K7: combine: out = Y0 + b2 + sum_t c_t (Y[1+t] + db2_t) ----------------
__global__ void k_combine(const float* __restrict__ Y,
                          const float* __restrict__ coefs,
                          const float* __restrict__ b2,
                          const float* __restrict__ db2,
                          float* __restrict__ out) {
  int idx = blockIdx.x * 256 + threadIdx.x;
  int b = idx / DIM, e = idx % DIM;
  float v = Y[(size_t)b * DIM + e] + b2[e];
#pragma unroll
  for (int t = 0; t < NT; t++) {
    float c = coefs[b * NT + t];
    v += c * (Y[((size_t)(1 + t) * 64 + b) * DIM + e] + db2[(size_t)t * DIM + e]);
  }
  out[idx] = v;
}

extern "C" void kernel_launch(void* const* d_in, const int* in_sizes, int n_in,
                              void* d_out, int out_size, void* d_ws, size_t ws_size,
                              hipStream_t stream) {
  const float* x   = (const float*)d_in[0];
  const float* W1  = (const float*)d_in[1];
  const float* b1  = (const float*)d_in[2];
  const float* W2  = (const float*)d_in[3];
  const float* b2  = (const float*)d_in[4];
  const float* dW1 = (const float*)d_in[5];
  const float* db1 = (const float*)d_in[6];
  const float* dW2 = (const float*)d_in[7];
  const float* db2 = (const float*)d_in[8];
  const float* mw1 = (const float*)d_in[9];
  const float* mb1 = (const float*)d_in[10];
  const float* mw2 = (const float*)d_in[11];
  const float* mb2 = (const float*)d_in[12];
  float* out = (float*)d_out;
  (void)in_sizes; (void)n_in; (void)out_size; (void)ws_size;

  // workspace layout (bytes) — total ~48.8 MB
  char* ws = (char*)d_ws;
  bf16*  A_bf    = (bf16*) (ws);                 // 25,165,824
  bf16*  WT      = (bf16*) (ws + 25165824);      // 21,233,664 -> 46,399,488
  float* pooledA = (float*)(ws + 46399488);      //    196,608 -> 46,596,096
  float* pooledB = (float*)(ws + 46596096);      //    196,608 -> 46,792,704
  float* coefs   = (float*)(ws + 46792704);      //      2,048 -> 46,794,752
  float* base    = (float*)(ws + 46794752);      //    196,608 -> 46,991,360
  float* Y       = (float*)(ws + 46991360);      //  1,769,472 -> 48,760,832

  k_patchify<<<dim3((BATCH * NPAD * (DIM / 4)) / 256), 256, 0, stream>>>(x, A_bf);
  k_transpose_cast<<<dim3(24, 24, 18), 256, 0, stream>>>(W1, dW1, W2, dW2, WT);
  // phase A
  k_gemm_pool<0><<<dim3(BATCH, DIM / 64), 256, 0, stream>>>(A_bf, WT, b1, db1, nullptr, pooledA);
  k_gemm2<<<dim3(DIM / 64, 1), 256, 0, stream>>>(pooledA, WT, 9, b2, base);
  k_metanet<<<dim3(BATCH), 192, 0, stream>>>(base, mw1, mb1, mw2, mb2, coefs);
  // phase B (inline mix from L2-resident WT)
  k_gemm_pool<1><<<dim3(BATCH, DIM / 64), 256, 0, stream>>>(A_bf, WT, b1, db1, coefs, pooledB);
  k_gemm2<<<dim3(DIM / 64, 9), 256, 0, stream>>>(pooledB, WT, 9, nullptr, Y);
  k_combine<<<dim3((BATCH * DIM) / 256), 256, 0, stream>>>(Y, coefs, b2, db2, out);
}